// Round 2
// baseline (388.626 us; speedup 1.0000x reference)
//
#include <hip/hip_runtime.h>

// out[b,o] = sum_e ( relu(relu(x[b,e,:]@W1[e]+b1[e])@W2[e]+b2[e]) @ W3[e] + b3[e] )
// E=16, DIN=128, H=512, DOUT=64, B=8192.  94.5 GFLOP -> compute-bound, bf16 MFMA.
//
// R2: latency-bound fix (R1: MfmaUtil 14%, Occ 23%).
//  - one expert per WG (grid 128x16=2048): WG turnover covers barrier stalls.
//  - x-tile staged to LDS (coalesced fp32 read -> bf16 swizzled, 16KB; total LDS 80KB = 2 WG/CU).
//  - layer 3 uses all 8 waves (2 of 16 output tiles each).
//  - next-phase B-fragments issued before each barrier (latency overlaps drain).
//  - per-WG result added to out via hardware fp32 atomics (out pre-zeroed).

#define NE   16
#define NDIN 128
#define NH   512
#define NDO  64
#define NB   8192

using bf16x8 = __attribute__((ext_vector_type(8))) __bf16;
using f32x4  = __attribute__((ext_vector_type(4))) float;

__device__ __forceinline__ unsigned short f2bf(float f) {
    union { float f; unsigned u; } v; v.f = f;
    unsigned r = v.u + 0x7FFFu + ((v.u >> 16) & 1u);   // RNE
    return (unsigned short)(r >> 16);
}

__device__ __forceinline__ bf16x8 cvt8(float4 a, float4 b) {
    union { unsigned short s[8]; bf16x8 v; } r;
    r.s[0] = f2bf(a.x); r.s[1] = f2bf(a.y); r.s[2] = f2bf(a.z); r.s[3] = f2bf(a.w);
    r.s[4] = f2bf(b.x); r.s[5] = f2bf(b.y); r.s[6] = f2bf(b.z); r.s[7] = f2bf(b.w);
    return r.v;
}

__device__ __forceinline__ f32x4 fzero() { f32x4 z = {0.f, 0.f, 0.f, 0.f}; return z; }

// Swizzled index (ushort units) into the 64x512 bf16 H tile: 16B granules XOR'd by row&15.
__device__ __forceinline__ int shidx(int m, int n) {
    return m * NH + (((n >> 3) ^ (m & 15)) << 3) + (n & 7);
}
// Same for the 64x128 x tile (16 granules per row).
__device__ __forceinline__ int shx(int m, int n) {
    return m * NDIN + ((((n >> 3) ^ (m & 15)) & 15) << 3) + (n & 7);
}

// ---------------- merged prep: fp32 [e][R][C] -> bf16 [e][C][R], all 3 weights ----------------
__global__ __launch_bounds__(256) void prep_weights(
    const float* __restrict__ W1, const float* __restrict__ W2, const float* __restrict__ W3,
    unsigned short* __restrict__ W1t, unsigned short* __restrict__ W2t, unsigned short* __restrict__ W3t)
{
    __shared__ float tile[64][65];
    const int t = blockIdx.x, e = blockIdx.y;
    const float* src; unsigned short* dst; int R, C, tr, tc;
    if (t < 16)      { src = W1; dst = W1t; R = NDIN; C = NH;  tr = t >> 3;        tc = t & 7;  }
    else if (t < 80) { src = W2; dst = W2t; R = NH;   C = NH;  tr = (t - 16) >> 3; tc = (t - 16) & 7; }
    else             { src = W3; dst = W3t; R = NH;   C = NDO; tr = t - 80;        tc = 0;      }
    const int r0 = tr * 64, c0 = tc * 64;
    const float* s = src + (size_t)e * R * C;
    unsigned short* d = dst + (size_t)e * R * C;
    const int tt = threadIdx.x;
#pragma unroll
    for (int i = 0; i < 4; ++i) {
        int f = i * 256 + tt;
        int r = f >> 4, c4 = (f & 15) * 4;
        const float4 v = *(const float4*)(s + (size_t)(r0 + r) * C + c0 + c4);
        tile[r][c4 + 0] = v.x; tile[r][c4 + 1] = v.y;
        tile[r][c4 + 2] = v.z; tile[r][c4 + 3] = v.w;
    }
    __syncthreads();
#pragma unroll
    for (int i = 0; i < 4; ++i) {
        int f = i * 256 + tt;
        int cc = f >> 4, rb = (f & 15) * 4;
        ushort4 o;
        o.x = f2bf(tile[rb + 0][cc]);
        o.y = f2bf(tile[rb + 1][cc]);
        o.z = f2bf(tile[rb + 2][cc]);
        o.w = f2bf(tile[rb + 3][cc]);
        *(ushort4*)(d + (size_t)(c0 + cc) * R + r0 + rb) = o;
    }
}

// ---------------- fused 3-layer expert MLP: one expert x 64 rows per WG ----------------
__global__ __launch_bounds__(512, 4) void moe_fused(
    const float* __restrict__ x,            // [B][E][DIN]
    const float* __restrict__ b1,           // [E][H]
    const float* __restrict__ b2,           // [E][H]
    const float* __restrict__ b3,           // [E][DOUT]
    const unsigned short* __restrict__ W1t, // [E][H][DIN]  bf16
    const unsigned short* __restrict__ W2t, // [E][H][H]    bf16
    const unsigned short* __restrict__ W3t, // [E][DOUT][H] bf16
    float* __restrict__ out)                // [B][DOUT]  (pre-zeroed)
{
    __shared__ unsigned short sMem[64 * NDIN + 64 * NH];  // 16KB x-tile + 64KB H-tile = 80KB
    unsigned short* sX = sMem;
    unsigned short* sH = sMem + 64 * NDIN;

    const int tid  = threadIdx.x;
    const int wave = tid >> 6;
    const int lane = tid & 63;
    const int q    = lane >> 4;
    const int l16  = lane & 15;
    const int b0   = blockIdx.x * 64;
    const int e    = blockIdx.y;
    const int nb   = wave * 64;

    // ---- stage x tile: coalesced fp32 read -> bf16 swizzled LDS ----
#pragma unroll
    for (int i = 0; i < 2; ++i) {
        int g = tid + i * 512;                 // 1024 granules of 8 floats
        int row = g >> 4, c8 = (g & 15) * 8;
        const float* p = x + ((size_t)(b0 + row) * NE + e) * NDIN + c8;
        float4 u0 = *(const float4*)p;
        float4 u1 = *(const float4*)(p + 4);
        *(bf16x8*)&sX[shx(row, c8)] = cvt8(u0, u1);
    }
    // preload L1 kt0 B-frags (no LDS dependency) so latency overlaps the barrier
    const unsigned short* W1p = W1t + (size_t)e * NH * NDIN;
    bf16x8 pre_b[4];
#pragma unroll
    for (int n = 0; n < 4; ++n)
        pre_b[n] = *(const bf16x8*)(W1p + (size_t)(nb + n * 16 + l16) * NDIN + q * 8);
    __syncthreads();

    // ---------------- layer 1: sH = relu(X @ W1 + b1) ----------------
    {
        f32x4 acc[4][4];
#pragma unroll
        for (int m = 0; m < 4; ++m)
#pragma unroll
            for (int n = 0; n < 4; ++n) acc[m][n] = fzero();

        bf16x8 afr[2][4], bfr[2][4];
#pragma unroll
        for (int n = 0; n < 4; ++n) bfr[0][n] = pre_b[n];
#pragma unroll
        for (int m = 0; m < 4; ++m)
            afr[0][m] = *(const bf16x8*)&sX[shx(m * 16 + l16, q * 8)];

#pragma unroll
        for (int kt = 0; kt < 4; ++kt) {
            const int cur = kt & 1, nxt = cur ^ 1;
            if (kt < 3) {
                const int k1 = (kt + 1) * 32 + q * 8;
#pragma unroll
                for (int n = 0; n < 4; ++n)
                    bfr[nxt][n] = *(const bf16x8*)(W1p + (size_t)(nb + n * 16 + l16) * NDIN + k1);
#pragma unroll
                for (int m = 0; m < 4; ++m)
                    afr[nxt][m] = *(const bf16x8*)&sX[shx(m * 16 + l16, k1)];
            }
#pragma unroll
            for (int m = 0; m < 4; ++m)
#pragma unroll
                for (int n = 0; n < 4; ++n)
                    acc[m][n] = __builtin_amdgcn_mfma_f32_16x16x32_bf16(
                        afr[cur][m], bfr[cur][n], acc[m][n], 0, 0, 0);
        }
#pragma unroll
        for (int n = 0; n < 4; ++n) {
            const int col = nb + n * 16 + l16;
            const float bias = b1[e * NH + col];
#pragma unroll
            for (int m = 0; m < 4; ++m)
#pragma unroll
                for (int r = 0; r < 4; ++r) {
                    float v = acc[m][n][r] + bias;
                    sH[shidx(m * 16 + q * 4 + r, col)] = f2bf(fmaxf(v, 0.f));
                }
        }
    }
    // preload L2 kt0 B-frags before publishing H1
    const unsigned short* W2p = W2t + (size_t)e * NH * NH;
#pragma unroll
    for (int n = 0; n < 4; ++n)
        pre_b[n] = *(const bf16x8*)(W2p + (size_t)(nb + n * 16 + l16) * NH + q * 8);
    __syncthreads();

    // ---------------- layer 2: acc2 = H1 @ W2 ----------------
    f32x4 acc2[4][4];
#pragma unroll
    for (int m = 0; m < 4; ++m)
#pragma unroll
        for (int n = 0; n < 4; ++n) acc2[m][n] = fzero();
    {
        bf16x8 afr[2][4], bfr[2][4];
#pragma unroll
        for (int n = 0; n < 4; ++n) bfr[0][n] = pre_b[n];
#pragma unroll
        for (int m = 0; m < 4; ++m)
            afr[0][m] = *(const bf16x8*)&sH[shidx(m * 16 + l16, q * 8)];

#pragma unroll
        for (int kt = 0; kt < 16; ++kt) {
            const int cur = kt & 1, nxt = cur ^ 1;
            if (kt < 15) {
                const int k1 = (kt + 1) * 32 + q * 8;
#pragma unroll
                for (int n = 0; n < 4; ++n)
                    bfr[nxt][n] = *(const bf16x8*)(W2p + (size_t)(nb + n * 16 + l16) * NH + k1);
#pragma unroll
                for (int m = 0; m < 4; ++m)
                    afr[nxt][m] = *(const bf16x8*)&sH[shidx(m * 16 + l16, k1)];
            }
#pragma unroll
            for (int m = 0; m < 4; ++m)
#pragma unroll
                for (int n = 0; n < 4; ++n)
                    acc2[m][n] = __builtin_amdgcn_mfma_f32_16x16x32_bf16(
                        afr[cur][m], bfr[cur][n], acc2[m][n], 0, 0, 0);
        }
    }
    __syncthreads();   // all H1 reads complete before overwrite

    // write H2 = relu(acc2 + b2)
#pragma unroll
    for (int n = 0; n < 4; ++n) {
        const int col = nb + n * 16 + l16;
        const float bias = b2[e * NH + col];
#pragma unroll
        for (int m = 0; m < 4; ++m)
#pragma unroll
            for (int r = 0; r < 4; ++r) {
                float v = acc2[m][n][r] + bias;
                sH[shidx(m * 16 + q * 4 + r, col)] = f2bf(fmaxf(v, 0.f));
            }
    }
    // preload L3 kt0 B-frags before publishing H2
    const unsigned short* W3p = W3t + (size_t)e * NDO * NH;
    const int mi = wave >> 1;          // this wave's m-tile
    const int n0 = (wave & 1) * 2;     // this wave's two n-tiles
    bf16x8 pb3[2];
#pragma unroll
    for (int i = 0; i < 2; ++i)
        pb3[i] = *(const bf16x8*)(W3p + (size_t)((n0 + i) * 16 + l16) * NH + q * 8);
    __syncthreads();

    // ---------------- layer 3: all 8 waves, 2 output tiles each ----------------
    f32x4 oacc[2];
    oacc[0] = fzero(); oacc[1] = fzero();
    {
        bf16x8 afr[2], bfr[2][2];
        bfr[0][0] = pb3[0]; bfr[0][1] = pb3[1];
        afr[0] = *(const bf16x8*)&sH[shidx(mi * 16 + l16, q * 8)];

#pragma unroll
        for (int kt = 0; kt < 16; ++kt) {
            const int cur = kt & 1, nxt = cur ^ 1;
            if (kt < 15) {
                const int k1 = (kt + 1) * 32 + q * 8;
#pragma unroll
                for (int i = 0; i < 2; ++i)
                    bfr[nxt][i] = *(const bf16x8*)(W3p + (size_t)((n0 + i) * 16 + l16) * NH + k1);
                afr[nxt] = *(const bf16x8*)&sH[shidx(mi * 16 + l16, k1)];
            }
#pragma unroll
            for (int i = 0; i < 2; ++i)
                oacc[i] = __builtin_amdgcn_mfma_f32_16x16x32_bf16(
                    afr[cur], bfr[cur][i], oacc[i], 0, 0, 0);
        }
    }
    // per-expert contribution (incl. b3) -> global atomic accumulate
#pragma unroll
    for (int i = 0; i < 2; ++i) {
        const int col = (n0 + i) * 16 + l16;
        const float bs = b3[e * NDO + col];
#pragma unroll
        for (int r = 0; r < 4; ++r) {
            const int row = b0 + mi * 16 + q * 4 + r;
            unsafeAtomicAdd(out + (size_t)row * NDO + col, oacc[i][r] + bs);
        }
    }
}

extern "C" void kernel_launch(void* const* d_in, const int* in_sizes, int n_in,
                              void* d_out, int out_size, void* d_ws, size_t ws_size,
                              hipStream_t stream) {
    const float* x  = (const float*)d_in[0];
    const float* W1 = (const float*)d_in[1];
    const float* b1 = (const float*)d_in[2];
    const float* W2 = (const float*)d_in[3];
    const float* b2 = (const float*)d_in[4];
    const float* W3 = (const float*)d_in[5];
    const float* b3 = (const float*)d_in[6];
    float* out = (float*)d_out;

    unsigned short* W1t = (unsigned short*)d_ws;            // [E][H][DIN]
    unsigned short* W2t = W1t + (size_t)NE * NH * NDIN;     // [E][H][H]
    unsigned short* W3t = W2t + (size_t)NE * NH * NH;       // [E][DOUT][H]

    hipMemsetAsync(d_out, 0, (size_t)out_size * sizeof(float), stream);
    prep_weights<<<dim3(88, NE), 256, 0, stream>>>(W1, W2, W3, W1t, W2t, W3t);
    moe_fused<<<dim3(NB / 64, NE), 512, 0, stream>>>(x, b1, b2, b3, W1t, W2t, W3t, out);
}

// Round 3
// 351.300 us; speedup vs baseline: 1.1063x; 1.1063x over previous
//
#include <hip/hip_runtime.h>

// out[b,o] = sum_e ( relu(relu(x[b,e,:]@W1[e]+b1[e])@W2[e]+b2[e]) @ W3[e] + b3[e] )
// E=16, DIN=128, H=512, DOUT=64, B=8192.  94.5 GFLOP -> compute-bound, bf16 MFMA.
//
// R3: R2 structure, but __launch_bounds__(512, 2).
//   R2's (512,4) capped VGPRs at 64 (arg acts as waves/EU: k = w*4/(B/64); B=512, w=4
//   => 8 waves/SIMD => 64 VGPR) -> layer-2 working set (~128 regs) spilled to scratch:
//   WRITE_SIZE 311 MB, FETCH 224 MB, MfmaUtil 13%. (512,2) => 128-VGPR cap, no spill
//   (R1 allocated 120 with identical register demand).

#define NE   16
#define NDIN 128
#define NH   512
#define NDO  64
#define NB   8192

using bf16x8 = __attribute__((ext_vector_type(8))) __bf16;
using f32x4  = __attribute__((ext_vector_type(4))) float;

__device__ __forceinline__ unsigned short f2bf(float f) {
    union { float f; unsigned u; } v; v.f = f;
    unsigned r = v.u + 0x7FFFu + ((v.u >> 16) & 1u);   // RNE
    return (unsigned short)(r >> 16);
}

__device__ __forceinline__ bf16x8 cvt8(float4 a, float4 b) {
    union { unsigned short s[8]; bf16x8 v; } r;
    r.s[0] = f2bf(a.x); r.s[1] = f2bf(a.y); r.s[2] = f2bf(a.z); r.s[3] = f2bf(a.w);
    r.s[4] = f2bf(b.x); r.s[5] = f2bf(b.y); r.s[6] = f2bf(b.z); r.s[7] = f2bf(b.w);
    return r.v;
}

__device__ __forceinline__ f32x4 fzero() { f32x4 z = {0.f, 0.f, 0.f, 0.f}; return z; }

// Swizzled index (ushort units) into the 64x512 bf16 H tile: 16B granules XOR'd by row&15.
__device__ __forceinline__ int shidx(int m, int n) {
    return m * NH + (((n >> 3) ^ (m & 15)) << 3) + (n & 7);
}
// Same for the 64x128 x tile (16 granules per row).
__device__ __forceinline__ int shx(int m, int n) {
    return m * NDIN + ((((n >> 3) ^ (m & 15)) & 15) << 3) + (n & 7);
}

// ---------------- merged prep: fp32 [e][R][C] -> bf16 [e][C][R], all 3 weights ----------------
__global__ __launch_bounds__(256) void prep_weights(
    const float* __restrict__ W1, const float* __restrict__ W2, const float* __restrict__ W3,
    unsigned short* __restrict__ W1t, unsigned short* __restrict__ W2t, unsigned short* __restrict__ W3t)
{
    __shared__ float tile[64][65];
    const int t = blockIdx.x, e = blockIdx.y;
    const float* src; unsigned short* dst; int R, C, tr, tc;
    if (t < 16)      { src = W1; dst = W1t; R = NDIN; C = NH;  tr = t >> 3;        tc = t & 7;  }
    else if (t < 80) { src = W2; dst = W2t; R = NH;   C = NH;  tr = (t - 16) >> 3; tc = (t - 16) & 7; }
    else             { src = W3; dst = W3t; R = NH;   C = NDO; tr = t - 80;        tc = 0;      }
    const int r0 = tr * 64, c0 = tc * 64;
    const float* s = src + (size_t)e * R * C;
    unsigned short* d = dst + (size_t)e * R * C;
    const int tt = threadIdx.x;
#pragma unroll
    for (int i = 0; i < 4; ++i) {
        int f = i * 256 + tt;
        int r = f >> 4, c4 = (f & 15) * 4;
        const float4 v = *(const float4*)(s + (size_t)(r0 + r) * C + c0 + c4);
        tile[r][c4 + 0] = v.x; tile[r][c4 + 1] = v.y;
        tile[r][c4 + 2] = v.z; tile[r][c4 + 3] = v.w;
    }
    __syncthreads();
#pragma unroll
    for (int i = 0; i < 4; ++i) {
        int f = i * 256 + tt;
        int cc = f >> 4, rb = (f & 15) * 4;
        ushort4 o;
        o.x = f2bf(tile[rb + 0][cc]);
        o.y = f2bf(tile[rb + 1][cc]);
        o.z = f2bf(tile[rb + 2][cc]);
        o.w = f2bf(tile[rb + 3][cc]);
        *(ushort4*)(d + (size_t)(c0 + cc) * R + r0 + rb) = o;
    }
}

// ---------------- fused 3-layer expert MLP: one expert x 64 rows per WG ----------------
__global__ __launch_bounds__(512, 2) void moe_fused(
    const float* __restrict__ x,            // [B][E][DIN]
    const float* __restrict__ b1,           // [E][H]
    const float* __restrict__ b2,           // [E][H]
    const float* __restrict__ b3,           // [E][DOUT]
    const unsigned short* __restrict__ W1t, // [E][H][DIN]  bf16
    const unsigned short* __restrict__ W2t, // [E][H][H]    bf16
    const unsigned short* __restrict__ W3t, // [E][DOUT][H] bf16
    float* __restrict__ out)                // [B][DOUT]  (pre-zeroed)
{
    __shared__ unsigned short sMem[64 * NDIN + 64 * NH];  // 16KB x-tile + 64KB H-tile = 80KB
    unsigned short* sX = sMem;
    unsigned short* sH = sMem + 64 * NDIN;

    const int tid  = threadIdx.x;
    const int wave = tid >> 6;
    const int lane = tid & 63;
    const int q    = lane >> 4;
    const int l16  = lane & 15;
    const int b0   = blockIdx.x * 64;
    const int e    = blockIdx.y;
    const int nb   = wave * 64;

    // ---- stage x tile: coalesced fp32 read -> bf16 swizzled LDS ----
#pragma unroll
    for (int i = 0; i < 2; ++i) {
        int g = tid + i * 512;                 // 1024 granules of 8 floats
        int row = g >> 4, c8 = (g & 15) * 8;
        const float* p = x + ((size_t)(b0 + row) * NE + e) * NDIN + c8;
        float4 u0 = *(const float4*)p;
        float4 u1 = *(const float4*)(p + 4);
        *(bf16x8*)&sX[shx(row, c8)] = cvt8(u0, u1);
    }
    // preload L1 kt0 B-frags (no LDS dependency) so latency overlaps the barrier
    const unsigned short* W1p = W1t + (size_t)e * NH * NDIN;
    bf16x8 pre_b[4];
#pragma unroll
    for (int n = 0; n < 4; ++n)
        pre_b[n] = *(const bf16x8*)(W1p + (size_t)(nb + n * 16 + l16) * NDIN + q * 8);
    __syncthreads();

    // ---------------- layer 1: sH = relu(X @ W1 + b1) ----------------
    {
        f32x4 acc[4][4];
#pragma unroll
        for (int m = 0; m < 4; ++m)
#pragma unroll
            for (int n = 0; n < 4; ++n) acc[m][n] = fzero();

        bf16x8 afr[2][4], bfr[2][4];
#pragma unroll
        for (int n = 0; n < 4; ++n) bfr[0][n] = pre_b[n];
#pragma unroll
        for (int m = 0; m < 4; ++m)
            afr[0][m] = *(const bf16x8*)&sX[shx(m * 16 + l16, q * 8)];

#pragma unroll
        for (int kt = 0; kt < 4; ++kt) {
            const int cur = kt & 1, nxt = cur ^ 1;
            if (kt < 3) {
                const int k1 = (kt + 1) * 32 + q * 8;
#pragma unroll
                for (int n = 0; n < 4; ++n)
                    bfr[nxt][n] = *(const bf16x8*)(W1p + (size_t)(nb + n * 16 + l16) * NDIN + k1);
#pragma unroll
                for (int m = 0; m < 4; ++m)
                    afr[nxt][m] = *(const bf16x8*)&sX[shx(m * 16 + l16, k1)];
            }
#pragma unroll
            for (int m = 0; m < 4; ++m)
#pragma unroll
                for (int n = 0; n < 4; ++n)
                    acc[m][n] = __builtin_amdgcn_mfma_f32_16x16x32_bf16(
                        afr[cur][m], bfr[cur][n], acc[m][n], 0, 0, 0);
        }
#pragma unroll
        for (int n = 0; n < 4; ++n) {
            const int col = nb + n * 16 + l16;
            const float bias = b1[e * NH + col];
#pragma unroll
            for (int m = 0; m < 4; ++m)
#pragma unroll
                for (int r = 0; r < 4; ++r) {
                    float v = acc[m][n][r] + bias;
                    sH[shidx(m * 16 + q * 4 + r, col)] = f2bf(fmaxf(v, 0.f));
                }
        }
    }
    // preload L2 kt0 B-frags before publishing H1
    const unsigned short* W2p = W2t + (size_t)e * NH * NH;
#pragma unroll
    for (int n = 0; n < 4; ++n)
        pre_b[n] = *(const bf16x8*)(W2p + (size_t)(nb + n * 16 + l16) * NH + q * 8);
    __syncthreads();

    // ---------------- layer 2: acc2 = H1 @ W2 ----------------
    f32x4 acc2[4][4];
#pragma unroll
    for (int m = 0; m < 4; ++m)
#pragma unroll
        for (int n = 0; n < 4; ++n) acc2[m][n] = fzero();
    {
        bf16x8 afr[2][4], bfr[2][4];
#pragma unroll
        for (int n = 0; n < 4; ++n) bfr[0][n] = pre_b[n];
#pragma unroll
        for (int m = 0; m < 4; ++m)
            afr[0][m] = *(const bf16x8*)&sH[shidx(m * 16 + l16, q * 8)];

#pragma unroll
        for (int kt = 0; kt < 16; ++kt) {
            const int cur = kt & 1, nxt = cur ^ 1;
            if (kt < 15) {
                const int k1 = (kt + 1) * 32 + q * 8;
#pragma unroll
                for (int n = 0; n < 4; ++n)
                    bfr[nxt][n] = *(const bf16x8*)(W2p + (size_t)(nb + n * 16 + l16) * NH + k1);
#pragma unroll
                for (int m = 0; m < 4; ++m)
                    afr[nxt][m] = *(const bf16x8*)&sH[shidx(m * 16 + l16, k1)];
            }
#pragma unroll
            for (int m = 0; m < 4; ++m)
#pragma unroll
                for (int n = 0; n < 4; ++n)
                    acc2[m][n] = __builtin_amdgcn_mfma_f32_16x16x32_bf16(
                        afr[cur][m], bfr[cur][n], acc2[m][n], 0, 0, 0);
        }
    }
    __syncthreads();   // all H1 reads complete before overwrite

    // write H2 = relu(acc2 + b2)
#pragma unroll
    for (int n = 0; n < 4; ++n) {
        const int col = nb + n * 16 + l16;
        const float bias = b2[e * NH + col];
#pragma unroll
        for (int m = 0; m < 4; ++m)
#pragma unroll
            for (int r = 0; r < 4; ++r) {
                float v = acc2[m][n][r] + bias;
                sH[shidx(m * 16 + q * 4 + r, col)] = f2bf(fmaxf(v, 0.f));
            }
    }
    // preload L3 kt0 B-frags before publishing H2
    const unsigned short* W3p = W3t + (size_t)e * NDO * NH;
    const int mi = wave >> 1;          // this wave's m-tile
    const int n0 = (wave & 1) * 2;     // this wave's two n-tiles
    bf16x8 pb3[2];
#pragma unroll
    for (int i = 0; i < 2; ++i)
        pb3[i] = *(const bf16x8*)(W3p + (size_t)((n0 + i) * 16 + l16) * NH + q * 8);
    __syncthreads();

    // ---------------- layer 3: all 8 waves, 2 output tiles each ----------------
    f32x4 oacc[2];
    oacc[0] = fzero(); oacc[1] = fzero();
    {
        bf16x8 afr[2], bfr[2][2];
        bfr[0][0] = pb3[0]; bfr[0][1] = pb3[1];
        afr[0] = *(const bf16x8*)&sH[shidx(mi * 16 + l16, q * 8)];

#pragma unroll
        for (int kt = 0; kt < 16; ++kt) {
            const int cur = kt & 1, nxt = cur ^ 1;
            if (kt < 15) {
                const int k1 = (kt + 1) * 32 + q * 8;
#pragma unroll
                for (int i = 0; i < 2; ++i)
                    bfr[nxt][i] = *(const bf16x8*)(W3p + (size_t)((n0 + i) * 16 + l16) * NH + k1);
                afr[nxt] = *(const bf16x8*)&sH[shidx(mi * 16 + l16, k1)];
            }
#pragma unroll
            for (int i = 0; i < 2; ++i)
                oacc[i] = __builtin_amdgcn_mfma_f32_16x16x32_bf16(
                    afr[cur], bfr[cur][i], oacc[i], 0, 0, 0);
        }
    }
    // per-expert contribution (incl. b3) -> global atomic accumulate
#pragma unroll
    for (int i = 0; i < 2; ++i) {
        const int col = (n0 + i) * 16 + l16;
        const float bs = b3[e * NDO + col];
#pragma unroll
        for (int r = 0; r < 4; ++r) {
            const int row = b0 + mi * 16 + q * 4 + r;
            unsafeAtomicAdd(out + (size_t)row * NDO + col, oacc[i][r] + bs);
        }
    }
}

extern "C" void kernel_launch(void* const* d_in, const int* in_sizes, int n_in,
                              void* d_out, int out_size, void* d_ws, size_t ws_size,
                              hipStream_t stream) {
    const float* x  = (const float*)d_in[0];
    const float* W1 = (const float*)d_in[1];
    const float* b1 = (const float*)d_in[2];
    const float* W2 = (const float*)d_in[3];
    const float* b2 = (const float*)d_in[4];
    const float* W3 = (const float*)d_in[5];
    const float* b3 = (const float*)d_in[6];
    float* out = (float*)d_out;

    unsigned short* W1t = (unsigned short*)d_ws;            // [E][H][DIN]
    unsigned short* W2t = W1t + (size_t)NE * NH * NDIN;     // [E][H][H]
    unsigned short* W3t = W2t + (size_t)NE * NH * NH;       // [E][DOUT][H]

    hipMemsetAsync(d_out, 0, (size_t)out_size * sizeof(float), stream);
    prep_weights<<<dim3(88, NE), 256, 0, stream>>>(W1, W2, W3, W1t, W2t, W3t);
    moe_fused<<<dim3(NB / 64, NE), 512, 0, stream>>>(x, b1, b2, b3, W1t, W2t, W3t, out);
}

// Round 5
// 312.630 us; speedup vs baseline: 1.2431x; 1.1237x over previous
//
#include <hip/hip_runtime.h>

// out[b,o] = sum_e ( relu(relu(x[b,e,:]@W1[e]+b1[e])@W2[e]+b2[e]) @ W3[e] + b3[e] )
// E=16, DIN=128, H=512, DOUT=64, B=8192.  94.5 GFLOP.
//
// R5 = R4 with the L3 buffer bug fixed.
//   R4 bug: a3f[4] with pre=(kt+4)&3 == cur -> prefetch overwrote the chunk being
//   consumed (L3 computed with wrong H2 chunks for kt=0..11; absmax 1.79).
//   Fix: lookahead-3 in 4 slots (pre=(kt+3)&3 != cur), 3 chunks preloaded.
// R4 design (unchanged): triple-buffered depth-2 prefetch of A/B frags in L1/L2;
//   L3 wave=(m-pair,n-tile) with all 16 B3 frags in regs before the H2 barrier;
//   per-n weight base pointers + compile-time k immediates; swizzle = base+((kt^hi2)<<5).

#define NE   16
#define NDIN 128
#define NH   512
#define NDO  64
#define NB   8192

using bf16x8 = __attribute__((ext_vector_type(8))) __bf16;
using f32x4  = __attribute__((ext_vector_type(4))) float;

__device__ __forceinline__ unsigned short f2bf(float f) {
    union { float f; unsigned u; } v; v.f = f;
    unsigned r = v.u + 0x7FFFu + ((v.u >> 16) & 1u);   // RNE
    return (unsigned short)(r >> 16);
}

__device__ __forceinline__ bf16x8 cvt8(float4 a, float4 b) {
    union { unsigned short s[8]; bf16x8 v; } r;
    r.s[0] = f2bf(a.x); r.s[1] = f2bf(a.y); r.s[2] = f2bf(a.z); r.s[3] = f2bf(a.w);
    r.s[4] = f2bf(b.x); r.s[5] = f2bf(b.y); r.s[6] = f2bf(b.z); r.s[7] = f2bf(b.w);
    return r.v;
}

__device__ __forceinline__ f32x4 fzero() { f32x4 z = {0.f, 0.f, 0.f, 0.f}; return z; }

// Swizzled index (ushort units): 16B granules XOR'd by row&15 (0 conflicts measured).
__device__ __forceinline__ int shidx(int m, int n) {          // H tile, stride 512
    return m * NH + (((n >> 3) ^ (m & 15)) << 3) + (n & 7);
}
__device__ __forceinline__ int shx(int m, int n) {            // X tile, stride 128
    return m * NDIN + ((((n >> 3) ^ (m & 15)) & 15) << 3) + (n & 7);
}

// ---------------- merged prep: fp32 [e][R][C] -> bf16 [e][C][R] ----------------
__global__ __launch_bounds__(256) void prep_weights(
    const float* __restrict__ W1, const float* __restrict__ W2, const float* __restrict__ W3,
    unsigned short* __restrict__ W1t, unsigned short* __restrict__ W2t, unsigned short* __restrict__ W3t)
{
    __shared__ float tile[64][65];
    const int t = blockIdx.x, e = blockIdx.y;
    const float* src; unsigned short* dst; int R, C, tr, tc;
    if (t < 16)      { src = W1; dst = W1t; R = NDIN; C = NH;  tr = t >> 3;        tc = t & 7;  }
    else if (t < 80) { src = W2; dst = W2t; R = NH;   C = NH;  tr = (t - 16) >> 3; tc = (t - 16) & 7; }
    else             { src = W3; dst = W3t; R = NH;   C = NDO; tr = t - 80;        tc = 0;      }
    const int r0 = tr * 64, c0 = tc * 64;
    const float* s = src + (size_t)e * R * C;
    unsigned short* d = dst + (size_t)e * R * C;
    const int tt = threadIdx.x;
#pragma unroll
    for (int i = 0; i < 4; ++i) {
        int f = i * 256 + tt;
        int r = f >> 4, c4 = (f & 15) * 4;
        const float4 v = *(const float4*)(s + (size_t)(r0 + r) * C + c0 + c4);
        tile[r][c4 + 0] = v.x; tile[r][c4 + 1] = v.y;
        tile[r][c4 + 2] = v.z; tile[r][c4 + 3] = v.w;
    }
    __syncthreads();
#pragma unroll
    for (int i = 0; i < 4; ++i) {
        int f = i * 256 + tt;
        int cc = f >> 4, rb = (f & 15) * 4;
        ushort4 o;
        o.x = f2bf(tile[rb + 0][cc]);
        o.y = f2bf(tile[rb + 1][cc]);
        o.z = f2bf(tile[rb + 2][cc]);
        o.w = f2bf(tile[rb + 3][cc]);
        *(ushort4*)(d + (size_t)(c0 + cc) * R + r0 + rb) = o;
    }
}

// ---------------- fused 3-layer expert MLP: one expert x 64 rows per WG ----------------
__global__ __launch_bounds__(512, 2) void moe_fused(
    const float* __restrict__ x,            // [B][E][DIN]
    const float* __restrict__ b1,           // [E][H]
    const float* __restrict__ b2,           // [E][H]
    const float* __restrict__ b3,           // [E][DOUT]
    const unsigned short* __restrict__ W1t, // [E][H][DIN]  bf16
    const unsigned short* __restrict__ W2t, // [E][H][H]    bf16
    const unsigned short* __restrict__ W3t, // [E][DOUT][H] bf16
    float* __restrict__ out)                // [B][DOUT]  (pre-zeroed)
{
    __shared__ unsigned short sMem[64 * NDIN + 64 * NH];  // 16KB X + 64KB H = 80KB
    unsigned short* sX = sMem;
    unsigned short* sH = sMem + 64 * NDIN;

    const int tid  = threadIdx.x;
    const int wave = tid >> 6;
    const int lane = tid & 63;
    const int q    = lane >> 4;
    const int l16  = lane & 15;
    const int hi2  = l16 >> 2;
    const int lo2  = l16 & 3;
    const int qe   = (q ^ lo2) * 8;       // swizzled in-granule element offset
    const int b0   = blockIdx.x * 64;
    const int e    = blockIdx.y;
    const int nb   = wave * 64;

    // per-wave LDS A-frag base offsets (elements);  read addr = base + ((kt^hi2)<<5)
    int aH[4], aX[4];
#pragma unroll
    for (int m = 0; m < 4; ++m) {
        aH[m] = (m * 16 + l16) * NH   + qe;
        aX[m] = (m * 16 + l16) * NDIN + qe;
    }

    // ---- x staging (global fp32 -> bf16 swizzled LDS), W1-B prologue in flight ----
    {
        const int r0 = tid >> 4, c8 = (tid & 15) * 8;
        const float* p0 = x + ((size_t)(b0 + r0)      * NE + e) * NDIN + c8;
        const float* p1 = x + ((size_t)(b0 + 32 + r0) * NE + e) * NDIN + c8;
        float4 u0 = *(const float4*)p0, u1 = *(const float4*)(p0 + 4);
        float4 u2 = *(const float4*)p1, u3 = *(const float4*)(p1 + 4);
        *(bf16x8*)&sX[shx(r0, c8)]      = cvt8(u0, u1);
        *(bf16x8*)&sX[shx(32 + r0, c8)] = cvt8(u2, u3);
    }

    const unsigned short* wb1[4];
#pragma unroll
    for (int n = 0; n < 4; ++n)
        wb1[n] = W1t + (size_t)e * NH * NDIN + (size_t)(nb + n * 16 + l16) * NDIN + q * 8;

    bf16x8 bfr[3][4], afr[3][4];
#pragma unroll
    for (int s = 0; s < 2; ++s)
#pragma unroll
        for (int n = 0; n < 4; ++n)
            bfr[s][n] = *(const bf16x8*)(wb1[n] + s * 32);
    float b1v[4];
#pragma unroll
    for (int n = 0; n < 4; ++n) b1v[n] = b1[e * NH + nb + n * 16 + l16];

    __syncthreads();   // sX visible (also drains the W1 prologue loads)

    // ---------------- layer 1: sH = relu(X @ W1 + b1), 4 kt ----------------
    f32x4 acc[4][4];
#pragma unroll
    for (int m = 0; m < 4; ++m)
#pragma unroll
        for (int n = 0; n < 4; ++n) acc[m][n] = fzero();

#pragma unroll
    for (int s = 0; s < 2; ++s)
#pragma unroll
        for (int m = 0; m < 4; ++m)
            afr[s][m] = *(const bf16x8*)&sX[aX[m] + (((s ^ hi2) & 3) << 5)];

#pragma unroll
    for (int kt = 0; kt < 4; ++kt) {
        const int cur = kt % 3, pre = (kt + 2) % 3;
        if (kt < 2) {
#pragma unroll
            for (int n = 0; n < 4; ++n)
                bfr[pre][n] = *(const bf16x8*)(wb1[n] + (kt + 2) * 32);
#pragma unroll
            for (int m = 0; m < 4; ++m)
                afr[pre][m] = *(const bf16x8*)&sX[aX[m] + ((((kt + 2) ^ hi2) & 3) << 5)];
        }
#pragma unroll
        for (int m = 0; m < 4; ++m)
#pragma unroll
            for (int n = 0; n < 4; ++n)
                acc[m][n] = __builtin_amdgcn_mfma_f32_16x16x32_bf16(
                    afr[cur][m], bfr[cur][n], acc[m][n], 0, 0, 0);
    }

    // W2-B prologue + b2 in flight over the H1 epilogue + barrier
    const unsigned short* wb2[4];
#pragma unroll
    for (int n = 0; n < 4; ++n)
        wb2[n] = W2t + (size_t)e * NH * NH + (size_t)(nb + n * 16 + l16) * NH + q * 8;
#pragma unroll
    for (int s = 0; s < 2; ++s)
#pragma unroll
        for (int n = 0; n < 4; ++n)
            bfr[s][n] = *(const bf16x8*)(wb2[n] + s * 32);
    float b2v[4];
#pragma unroll
    for (int n = 0; n < 4; ++n) b2v[n] = b2[e * NH + nb + n * 16 + l16];

    // H1 epilogue
#pragma unroll
    for (int n = 0; n < 4; ++n) {
        const int col = nb + n * 16 + l16;
#pragma unroll
        for (int m = 0; m < 4; ++m)
#pragma unroll
            for (int r = 0; r < 4; ++r) {
                float v = acc[m][n][r] + b1v[n];
                sH[shidx(m * 16 + q * 4 + r, col)] = f2bf(fmaxf(v, 0.f));
            }
    }
    __syncthreads();   // H1 visible

    // ---------------- layer 2: acc2 = H1 @ W2, 16 kt ----------------
    f32x4 acc2[4][4];
#pragma unroll
    for (int m = 0; m < 4; ++m)
#pragma unroll
        for (int n = 0; n < 4; ++n) acc2[m][n] = fzero();

#pragma unroll
    for (int s = 0; s < 2; ++s)
#pragma unroll
        for (int m = 0; m < 4; ++m)
            afr[s][m] = *(const bf16x8*)&sH[aH[m] + (((s ^ hi2)) << 5)];

#pragma unroll
    for (int kt = 0; kt < 16; ++kt) {
        const int cur = kt % 3, pre = (kt + 2) % 3;
        if (kt < 14) {
#pragma unroll
            for (int n = 0; n < 4; ++n)
                bfr[pre][n] = *(const bf16x8*)(wb2[n] + (kt + 2) * 32);
#pragma unroll
            for (int m = 0; m < 4; ++m)
                afr[pre][m] = *(const bf16x8*)&sH[aH[m] + ((((kt + 2) ^ hi2)) << 5)];
        }
#pragma unroll
        for (int m = 0; m < 4; ++m)
#pragma unroll
            for (int n = 0; n < 4; ++n)
                acc2[m][n] = __builtin_amdgcn_mfma_f32_16x16x32_bf16(
                    afr[cur][m], bfr[cur][n], acc2[m][n], 0, 0, 0);
    }

    // L3 mapping: wave -> (m-pair, n-tile): halves W3 dup, 8 waves cover 4x4 tiles.
    const int n3 = wave & 3, mp = wave >> 2;
    // prefetch ALL 16 B3 frags + b3 now; latency hides under epilogue + 2 barriers
    const unsigned short* wb3 = W3t + (size_t)e * NDO * NH + (size_t)(n3 * 16 + l16) * NH + q * 8;
    bf16x8 b3f[16];
#pragma unroll
    for (int kt = 0; kt < 16; ++kt) b3f[kt] = *(const bf16x8*)(wb3 + kt * 32);
    const float b3v = b3[e * NDO + n3 * 16 + l16];

    __syncthreads();   // all H1 reads complete before overwrite

    // H2 epilogue
#pragma unroll
    for (int n = 0; n < 4; ++n) {
        const int col = nb + n * 16 + l16;
#pragma unroll
        for (int m = 0; m < 4; ++m)
#pragma unroll
            for (int r = 0; r < 4; ++r) {
                float v = acc2[m][n][r] + b2v[n];
                sH[shidx(m * 16 + q * 4 + r, col)] = f2bf(fmaxf(v, 0.f));
            }
    }
    __syncthreads();   // H2 visible

    // ---------------- layer 3: O = H2 @ W3 (B in regs; A lookahead-3 in 4 slots) ----------------
    int a3[2];
#pragma unroll
    for (int i = 0; i < 2; ++i) a3[i] = ((2 * mp + i) * 16 + l16) * NH + qe;

    bf16x8 a3f[4][2];
#pragma unroll
    for (int s = 0; s < 3; ++s)          // preload chunks 0..2 (slot s = chunk s)
#pragma unroll
        for (int i = 0; i < 2; ++i)
            a3f[s][i] = *(const bf16x8*)&sH[a3[i] + (((s ^ hi2)) << 5)];

    f32x4 oacc[2];
    oacc[0] = fzero(); oacc[1] = fzero();
#pragma unroll
    for (int kt = 0; kt < 16; ++kt) {
        const int cur = kt & 3;
        if (kt < 13) {                   // prefetch chunk kt+3 into slot (kt+3)&3 != cur
            const int pre = (kt + 3) & 3;
#pragma unroll
            for (int i = 0; i < 2; ++i)
                a3f[pre][i] = *(const bf16x8*)&sH[a3[i] + ((((kt + 3) ^ hi2)) << 5)];
        }
#pragma unroll
        for (int i = 0; i < 2; ++i)
            oacc[i] = __builtin_amdgcn_mfma_f32_16x16x32_bf16(
                a3f[cur][i], b3f[kt], oacc[i], 0, 0, 0);
    }

    // final: per-expert contribution -> global fp32 atomics
#pragma unroll
    for (int i = 0; i < 2; ++i) {
        const int col = n3 * 16 + l16;
#pragma unroll
        for (int r = 0; r < 4; ++r) {
            const int row = b0 + (2 * mp + i) * 16 + q * 4 + r;
            unsafeAtomicAdd(out + (size_t)row * NDO + col, oacc[i][r] + b3v);
        }
    }
}

extern "C" void kernel_launch(void* const* d_in, const int* in_sizes, int n_in,
                              void* d_out, int out_size, void* d_ws, size_t ws_size,
                              hipStream_t stream) {
    const float* x  = (const float*)d_in[0];
    const float* W1 = (const float*)d_in[1];
    const float* b1 = (const float*)d_in[2];
    const float* W2 = (const float*)d_in[3];
    const float* b2 = (const float*)d_in[4];
    const float* W3 = (const float*)d_in[5];
    const float* b3 = (const float*)d_in[6];
    float* out = (float*)d_out;

    unsigned short* W1t = (unsigned short*)d_ws;            // [E][H][DIN]
    unsigned short* W2t = W1t + (size_t)NE * NH * NDIN;     // [E][H][H]
    unsigned short* W3t = W2t + (size_t)NE * NH * NH;       // [E][DOUT][H]

    hipMemsetAsync(d_out, 0, (size_t)out_size * sizeof(float), stream);
    prep_weights<<<dim3(88, NE), 256, 0, stream>>>(W1, W2, W3, W1t, W2t, W3t);
    moe_fused<<<dim3(NB / 64, NE), 512, 0, stream>>>(x, b1, b2, b3, W1t, W2t, W3t, out);
}